// Round 10
// baseline (154.439 us; speedup 1.0000x reference)
//
#include <hip/hip_runtime.h>

#define B 8
#define CCH 3
#define HH 512
#define WW 512
#define PAD 10
#define TSX 32
#define TSY 32
#define PTY 52                 // padded rows per tile
#define HSH 53                 // hs rows per column
#define NT 256                 // waves 0-1: producers, waves 2-3: consumers

// One barrier per batch. Producers compute hsum(b+1) from GLOBAL (no tile in
// LDS at all) into hs[(b+1)&1] while consumers run vert(b) from hs[b&1].
__global__ __launch_bounds__(NT, 3) void nlm_fused_kernel(const float* __restrict__ noisy,
                                                          float* __restrict__ out) {
    __shared__ float2 hs[2][TSX][HSH];     // 27136 B

    const int tid = threadIdx.x;
    const int x0 = blockIdx.x * TSX;
    const int y0 = blockIdx.y * TSY;
    const int ch = blockIdx.z;
    const bool is_prod = (tid < 128);

    const float kE = (-100.0f / 441.0f) * 1.44269504088896f;  // 1/h^2 * 1/n * 1/ln2

    // ================= producer state (tid 0..127; 104 active) =================
    // unit = (row 0..51, segment 0/16). Reads 40 aligned floats from global,
    // computes 16 sliding (s1,s2), writes hs[n][seg..seg+15][row].
    const bool pact = is_prod && (tid < PTY * 2);
    const int  prow = tid >> 1;
    const int  pseg = (tid & 1) << 4;
    int prowbase = 0, pgx0 = 0;
    bool pedge = false;
    if (is_prod) {
        int gy = y0 + prow - PAD;
        gy = (gy < 0) ? -gy : ((gy >= HH) ? (2 * (HH - 1) - gy) : gy);
        prowbase = gy * WW;
        pgx0 = x0 + pseg - 12;             // aligned; v[t] = padded col pseg-2+t
        pedge = (pgx0 < 0) || (pgx0 + 39 > WW - 1);
    }

    auto hsum = [&](int bb, int buf) {
        const float* src = noisy + (size_t)(bb * CCH + ch) * (HH * WW);
        float v[40];
        if (!pedge) {
            #pragma unroll
            for (int q = 0; q < 10; ++q)
                *(float4*)&v[q * 4] = *(const float4*)(src + prowbase + pgx0 + (q << 2));
        } else {
            #pragma unroll
            for (int t = 0; t < 40; ++t) {
                int gx = pgx0 + t;
                gx = (gx < 0) ? -gx : ((gx >= WW) ? (2 * (WW - 1) - gx) : gx);
                v[t] = src[prowbase + gx];
            }
        }
        // output j: padded cols pseg+j .. pseg+j+20  ->  v[j+2 .. j+22]
        float s1 = 0.f, s2 = 0.f;
        #pragma unroll
        for (int k = 2; k <= 22; ++k) { s1 += v[k]; s2 = fmaf(v[k], v[k], s2); }
        if (pact) hs[buf][pseg][prow] = make_float2(s1, s2);
        #pragma unroll
        for (int j = 1; j < 16; ++j) {
            float vo = v[j + 1], vn = v[j + 22];
            s1 += vn - vo;
            s2 += vn * vn - vo * vo;
            if (pact) hs[buf][pseg + j][prow] = make_float2(s1, s2);
        }
    };

    // ================= consumer state (tid 128..255) =================
    const int ctid = tid - 128;
    const int tx   = ctid & 31;
    const int cty0 = (ctid >> 5) << 3;     // 0,8,16,24: 8 rows per thread
    const int x    = x0 + tx;
    int px = x - PAD; px = (px < 0) ? -px : px;        // x-10 <= 501: low reflect only
    const int abase = (y0 + cty0) * WW + x;
    int poff[8];
    #pragma unroll
    for (int i = 0; i < 8; ++i) {
        int py = y0 + cty0 + i - PAD;
        py = (py < 0) ? -py : py;                      // py <= 501: low reflect only
        poff[i] = py * WW + px;
    }

    float avp[8], pvp[8];                  // prefetched a/p for the next batch
    auto ap_prefetch = [&](int bb) {
        const float* src = noisy + (size_t)(bb * CCH + ch) * (HH * WW);
        #pragma unroll
        for (int i = 0; i < 8; ++i) {
            avp[i] = src[abase + i * WW];
            pvp[i] = src[poff[i]];
        }
    };

    float num[8], den[8];
    #pragma unroll
    for (int i = 0; i < 8; ++i) { num[i] = 0.f; den[i] = 0.f; }

    // ================= prologue =================
    if (is_prod) {
        hsum(0, 0);
    } else {
        ap_prefetch(0);
    }
    __syncthreads();

    // ================= pipeline: 8 steps, 1 barrier each =================
    for (int b = 0; b < B; ++b) {
        if (is_prod) {
            if (b < B - 1) hsum(b + 1, (b + 1) & 1);
        } else {
            const int cur = b & 1;
            float av[8], pv[8];
            #pragma unroll
            for (int i = 0; i < 8; ++i) { av[i] = avp[i]; pv[i] = pvp[i]; }
            if (b < B - 1) ap_prefetch(b + 1);   // in flight behind vert compute

            float2 hh[21];
            #pragma unroll
            for (int k = 0; k < 21; ++k) hh[k] = hs[cur][tx][cty0 + k];
            float vs1 = 0.f, vs2 = 0.f;
            #pragma unroll
            for (int k = 0; k < 21; ++k) { vs1 += hh[k].x; vs2 += hh[k].y; }
            {
                float a = av[0];
                float dd = fmaf(a, fmaf(441.f, a, -2.f * vs1), vs2);
                float w = exp2f(dd * kE);
                num[0] += w * pv[0]; den[0] += w;
            }
            #pragma unroll
            for (int i = 1; i < 8; ++i) {
                float2 hn = hs[cur][tx][cty0 + 20 + i];
                vs1 += hn.x - hh[i - 1].x;
                vs2 += hn.y - hh[i - 1].y;
                float a = av[i];
                float dd = fmaf(a, fmaf(441.f, a, -2.f * vs1), vs2);
                float w = exp2f(dd * kE);
                num[i] += w * pv[i]; den[i] += w;
            }
        }
        __syncthreads();
    }

    // ================= epilogue: consumers write all 8 batch slices =================
    if (!is_prod) {
        #pragma unroll
        for (int i = 0; i < 8; ++i) {
            int y = y0 + cty0 + i;
            float v = num[i] / (den[i] + 1e-10f);
            v = v < 0.f ? 0.f : (v > 1.f ? 1.f : v);
            #pragma unroll
            for (int b = 0; b < B; ++b)
                out[((size_t)(b * CCH + ch) * HH + y) * WW + x] = v;
        }
    }
}

extern "C" void kernel_launch(void* const* d_in, const int* in_sizes, int n_in,
                              void* d_out, int out_size, void* d_ws, size_t ws_size,
                              hipStream_t stream) {
    const float* noisy = (const float*)d_in[0];
    float* out = (float*)d_out;
    dim3 grid(WW / TSX, HH / TSY, CCH);
    nlm_fused_kernel<<<grid, dim3(NT), 0, stream>>>(noisy, out);
}